// Round 7
// baseline (688.404 us; speedup 1.0000x reference)
//
#include <hip/hip_runtime.h>
#include <hip/hip_bf16.h>

#define EMB 128
#define NPB 256          // nodes per bucket (matches >>8 and phase-B blockDim)
#define NB_PAD 512
#define CHUNK 4096       // edges per bucket_scatter/count block

typedef unsigned int uint32;
typedef __attribute__((ext_vector_type(8))) short bf16x8;
typedef __attribute__((ext_vector_type(4))) float f32x4;

__device__ __forceinline__ ushort f2bf(float f) {  // RNE, finite values
    uint32 u = __float_as_uint(f);
    return (ushort)((u + 0x7fff + ((u >> 16) & 1)) >> 16);
}
// pack bf16(RTZ) of x0 (low) and x1 (high) into one dword
__device__ __forceinline__ uint32 pack_hi2(uint32 u0, uint32 u1) {
    return (u1 & 0xffff0000u) | (u0 >> 16);
}

// ---------------- bucket histogram of dst>>8 ----------------

__global__ __launch_bounds__(256) void bucket_count_kernel(
    const int* __restrict__ dst, int* __restrict__ bucket_cnt, int E, int NB) {
    __shared__ int cnt[NB_PAD];
    int t = threadIdx.x;
    long e0 = (long)blockIdx.x * CHUNK;
    int n = E - (int)e0; if (n > CHUNK) n = CHUNK;
    for (int b = t; b < NB_PAD; b += 256) cnt[b] = 0;
    __syncthreads();
    #pragma unroll
    for (int i = 0; i < CHUNK / 256; i++) {
        int idx = t + i * 256;
        if (idx < n) atomicAdd(&cnt[dst[e0 + idx] >> 8], 1);
    }
    __syncthreads();
    for (int b = t; b < NB; b += 256)
        if (cnt[b] > 0) atomicAdd(&bucket_cnt[b], cnt[b]);
}

// exclusive scan of bucket_cnt[NB] (NB<=512) -> ebase[NB+1], gcursor[NB]
__global__ void bucket_scan_kernel(const int* __restrict__ bucket_cnt,
                                   int* __restrict__ ebase, int* __restrict__ gcursor,
                                   int NB, int E) {
    __shared__ int sc[512];
    int t = threadIdx.x;
    int v = (t < NB) ? bucket_cnt[t] : 0;
    sc[t] = v;
    __syncthreads();
    for (int off = 1; off < 512; off <<= 1) {
        int u = (t >= off) ? sc[t - off] : 0;
        __syncthreads();
        sc[t] += u;
        __syncthreads();
    }
    if (t < NB) {
        int excl = sc[t] - v;
        ebase[t] = excl;
        gcursor[t] = excl;
    }
    if (t == 0) ebase[NB] = E;
}

// ---------------- Phase A: scatter edges into bucket-grouped (src,dst) pairs ----------------

__global__ __launch_bounds__(256) void bucket_scatter_kernel(
    const int* __restrict__ src, const int* __restrict__ dst,
    int* __restrict__ gcursor, uint2* __restrict__ ebuf, int E, int NB) {
    __shared__ int cnt[NB_PAD];
    __shared__ int loff[NB_PAD];
    __shared__ int gbase[NB_PAD];
    __shared__ int pos[NB_PAD];
    __shared__ int sc[256];
    __shared__ uint2 stage[CHUNK];
    int t = threadIdx.x;
    long e0 = (long)blockIdx.x * CHUNK;
    int n = E - (int)e0; if (n > CHUNK) n = CHUNK;
    for (int b = t; b < NB_PAD; b += 256) { cnt[b] = 0; pos[b] = 0; }
    __syncthreads();
    int es[CHUNK / 256], ed[CHUNK / 256];
    #pragma unroll
    for (int i = 0; i < CHUNK / 256; i++) {
        int idx = t + i * 256;
        if (idx < n) {
            es[i] = src[e0 + idx];
            ed[i] = dst[e0 + idx];
            atomicAdd(&cnt[ed[i] >> 8], 1);
        }
    }
    __syncthreads();
    // exclusive scan of cnt[0..511] -> loff
    int a = cnt[2 * t], b2 = cnt[2 * t + 1];
    sc[t] = a + b2;
    __syncthreads();
    for (int off = 1; off < 256; off <<= 1) {
        int v = (t >= off) ? sc[t - off] : 0;
        __syncthreads();
        sc[t] += v;
        __syncthreads();
    }
    int excl = sc[t] - (a + b2);
    loff[2 * t] = excl;
    loff[2 * t + 1] = excl + a;
    __syncthreads();
    // reserve global ranges (one atomic per non-empty bucket per block)
    for (int b = t; b < NB; b += 256)
        if (cnt[b] > 0) gbase[b] = atomicAdd(&gcursor[b], cnt[b]);
    __syncthreads();
    // group edges by bucket in LDS staging
    #pragma unroll
    for (int i = 0; i < CHUNK / 256; i++) {
        int idx = t + i * 256;
        if (idx < n) {
            int b = ed[i] >> 8;
            int p = atomicAdd(&pos[b], 1);
            stage[loff[b] + p] = make_uint2((uint32)es[i], (uint32)ed[i]);
        }
    }
    __syncthreads();
    // write contiguous runs per bucket
    for (int b = t; b < NB; b += 256) {
        int c = cnt[b], lo = loff[b], go = gbase[b];
        for (int k = 0; k < c; k++) ebuf[go + k] = stage[lo + k];
    }
}

// ---------------- per-bucket degree + dinv (coalesced writes, LDS atomics) ----------------

__global__ __launch_bounds__(256) void bucket_deg_kernel(
    const uint2* __restrict__ ebuf, const int* __restrict__ ebase,
    int* __restrict__ deg, float* __restrict__ dinv, int N) {
    __shared__ int cnt[NPB];
    int t = threadIdx.x;
    int n0 = blockIdx.x * NPB;
    int nn = N - n0; if (nn > NPB) nn = NPB;
    cnt[t] = 0;
    __syncthreads();
    int e0 = ebase[blockIdx.x];
    int e1 = ebase[blockIdx.x + 1];
    for (int e = e0 + t; e < e1; e += 256) {
        uint2 sd = ebuf[e];
        atomicAdd(&cnt[(int)sd.y - n0], 1);
    }
    __syncthreads();
    if (t < nn) {
        int c = cnt[t];
        deg[n0 + t] = c;
        dinv[n0 + t] = c > 0 ? rsqrtf((float)c) : 0.0f;
    }
}

// ---------------- rowptr scan ----------------

__global__ void scan1_kernel(const int* __restrict__ deg, int* __restrict__ rowptr,
                             int* __restrict__ bsum, int N) {
    __shared__ int sc[256];
    int t = threadIdx.x;
    int base = blockIdx.x * 1024 + t * 4;
    int d0 = 0, d1 = 0, d2 = 0, d3 = 0;
    if (base + 3 < N) {
        int4 v = *(const int4*)(deg + base);
        d0 = v.x; d1 = v.y; d2 = v.z; d3 = v.w;
    } else {
        if (base     < N) d0 = deg[base];
        if (base + 1 < N) d1 = deg[base + 1];
        if (base + 2 < N) d2 = deg[base + 2];
        if (base + 3 < N) d3 = deg[base + 3];
    }
    int s = d0 + d1 + d2 + d3;
    sc[t] = s;
    __syncthreads();
    for (int off = 1; off < 256; off <<= 1) {
        int v = (t >= off) ? sc[t - off] : 0;
        __syncthreads();
        sc[t] += v;
        __syncthreads();
    }
    int excl = sc[t] - s;
    if (t == 255) bsum[blockIdx.x] = sc[255];
    int dd[4] = {d0, d1, d2, d3};
    int p = excl;
    #pragma unroll
    for (int j = 0; j < 4; j++) {
        int i = base + j;
        if (i < N) rowptr[i] = p;
        p += dd[j];
    }
}

__global__ void scan2_kernel(int* bsum, int nb) {  // nb <= 128
    __shared__ int sc[128];
    int t = threadIdx.x;
    int v = (t < nb) ? bsum[t] : 0;
    sc[t] = v;
    __syncthreads();
    for (int off = 1; off < 128; off <<= 1) {
        int u = (t >= off) ? sc[t - off] : 0;
        __syncthreads();
        sc[t] += u;
        __syncthreads();
    }
    if (t < nb) bsum[t] = sc[t] - v;  // exclusive
}

__global__ void scan3_kernel(int* __restrict__ rowptr, const int* __restrict__ bsum,
                             int N, int E) {
    int t = threadIdx.x, b = blockIdx.x;
    int add = bsum[b];
    int base = b * 1024 + t * 4;
    #pragma unroll
    for (int j = 0; j < 4; j++) {
        int i = base + j;
        if (i < N) rowptr[i] += add;
    }
    if (b == 0 && t == 0) rowptr[N] = E;
}

// ---------------- Phase B: per-bucket fill of csr (writes confined to one L2) ----------------

__global__ __launch_bounds__(256) void bucket_fill_kernel(
    const uint2* __restrict__ ebuf, const int* __restrict__ rowptr,
    int* __restrict__ csr, int N) {
    __shared__ int cnt[NPB];
    __shared__ int rp[NPB];
    int t = threadIdx.x;
    int n0 = blockIdx.x * NPB;
    int nn = N - n0; if (nn > NPB) nn = NPB;
    if (t < nn) { cnt[t] = 0; rp[t] = rowptr[n0 + t]; }
    __syncthreads();
    int e0 = rowptr[n0];
    int e1 = rowptr[n0 + nn];
    for (int e = e0 + t; e < e1; e += 256) {
        uint2 sd = ebuf[e];
        int local = (int)sd.y - n0;
        int p = atomicAdd(&cnt[local], 1);
        csr[rp[local] + p] = (int)sd.x;
    }
}

// ---------------- panel aggregation + ReLU ----------------
// Yhp panel-major: [8 panels][N][8 dwords] of bf16 pairs, ALREADY scaled by dinv[src].
// out[n][panel*16 + 2d..] = relu( dinv[n] * sum_{s in N(n)} Yhp[p][s][d] )
// Lane (ns = lane>>3, d = lane&7): 8 nodes x 8 dwords per wave; register accumulators,
// no shuffles/atomics. panel = blockIdx & 7 rides round-robin block->XCD dispatch so
// each XCD's L2 holds one resident 3.2 MB panel.

__global__ __launch_bounds__(256) void agg_panel_kernel(
    const uint32* __restrict__ Yhp,
    const int* __restrict__ rowptr, const int* __restrict__ csr,
    const float* __restrict__ dinv, float* __restrict__ out, int N) {
    int panel = blockIdx.x & 7;
    int wv = threadIdx.x >> 6, lane = threadIdx.x & 63;
    int ns = lane >> 3, d = lane & 7;
    int node = (blockIdx.x >> 3) * 32 + wv * 8 + ns;
    const uint32* pD = Yhp + (size_t)panel * N * 8;
    float ax = 0.0f, ay = 0.0f;
    int e = 0, ee = 0;
    if (node < N) { e = rowptr[node]; ee = rowptr[node + 1]; }
    while (__any(e < ee)) {
        uint32 p0 = 0, p1 = 0, p2 = 0, p3 = 0;
        if (e < ee)     p0 = pD[(size_t)csr[e] * 8 + d];
        if (e + 1 < ee) p1 = pD[(size_t)csr[e + 1] * 8 + d];
        if (e + 2 < ee) p2 = pD[(size_t)csr[e + 2] * 8 + d];
        if (e + 3 < ee) p3 = pD[(size_t)csr[e + 3] * 8 + d];
        ax += __uint_as_float(p0 << 16) + __uint_as_float(p1 << 16)
            + __uint_as_float(p2 << 16) + __uint_as_float(p3 << 16);
        ay += __uint_as_float(p0 & 0xffff0000u) + __uint_as_float(p1 & 0xffff0000u)
            + __uint_as_float(p2 & 0xffff0000u) + __uint_as_float(p3 & 0xffff0000u);
        e += 4;
    }
    if (node < N) {
        float wd = dinv[node];
        float2 r;
        r.x = fmaxf(ax * wd, 0.0f);
        r.y = fmaxf(ay * wd, 0.0f);
        *(float2*)(out + (size_t)node * EMB + panel * 16 + d * 2) = r;
    }
}

// ---------------- W split: WhiT/WloT[n][k] = bf16 split of W[k][n] (transposed) ----------------

__global__ void wsplit_kernel(const float* __restrict__ W0, const float* __restrict__ W1,
                              const float* __restrict__ W2,
                              ushort* __restrict__ Whi, ushort* __restrict__ Wlo) {
    const float* W = (blockIdx.x == 0) ? W0 : (blockIdx.x == 1) ? W1 : W2;
    ushort* hiT = Whi + blockIdx.x * EMB * EMB;
    ushort* loT = Wlo + blockIdx.x * EMB * EMB;
    for (int i = threadIdx.x; i < EMB * EMB; i += blockDim.x) {
        int k = i >> 7, n = i & 127;
        float w = W[i];
        uint32 u = __float_as_uint(w);
        ushort hi = (ushort)(u >> 16);                      // RTZ: exact remainder
        float hif = __uint_as_float(u & 0xffff0000u);
        ushort lo = f2bf(w - hif);                          // RNE of remainder
        hiT[n * EMB + k] = hi;
        loT[n * EMB + k] = lo;
    }
}

// ---------------- split-bf16 MFMA GEMM -> panel-major bf16, dinv folded ----------------
// Yhp[p][rowOff+row][l16] = f2bf( dinv[rowOff+row] * (A[row,:] @ W)[col] ), p = col>>4.
// x@w ~= xhi@whi + xhi@wlo + xlo@whi. Wave = one 16-row tile x 32 cols (wave wv ->
// cols [32wv,32wv+32)); A-fragments loaded straight from global (L1 covers reuse);
// B-fragments in registers for the whole dispatch; no LDS, no syncs.

union FragU { uint32 u[4]; bf16x8 v; };

__global__ __launch_bounds__(256) void gemm_mfma_kernel(
    const float* __restrict__ A, const ushort* __restrict__ WhiT,
    const ushort* __restrict__ WloT, const float* __restrict__ dinv,
    ushort* __restrict__ Yhp, int M, int rowOff, int Ntot) {
    int t = threadIdx.x;
    int wv = t >> 6, lane = t & 63, quad = lane >> 4, l16 = lane & 15;

    // B fragments: lane holds B[k = 32*(kc&3) + 8*quad + j][n = 32*wv + 16*c + l16]
    FragU bfr[8][2];
    #pragma unroll
    for (int kc = 0; kc < 8; kc++) {
        const ushort* srcW = (kc < 4) ? WhiT : WloT;
        int kb = (kc & 3) * 32 + quad * 8;
        #pragma unroll
        for (int c = 0; c < 2; c++) {
            int n = wv * 32 + c * 16 + l16;
            const uint32* p = (const uint32*)(srcW + n * EMB + kb);
            bfr[kc][c].u[0] = p[0];
            bfr[kc][c].u[1] = p[1];
            bfr[kc][c].u[2] = p[2];
            bfr[kc][c].u[3] = p[3];
        }
    }

    int ntile = (M + 15) >> 4;
    for (int tile = blockIdx.x; tile < ntile; tile += (int)gridDim.x) {
        int r0 = tile << 4;
        int arow = r0 + l16;
        bool rv = arow < M;
        const float* ap = A + (size_t)(rv ? arow : 0) * EMB + quad * 8;

        // load A[m=l16][k = 32kc + 8quad + j] as 8 independent float4s
        float4 xa[4], xb[4];
        #pragma unroll
        for (int kc = 0; kc < 4; kc++) {
            if (rv) {
                xa[kc] = *(const float4*)(ap + kc * 32);
                xb[kc] = *(const float4*)(ap + kc * 32 + 4);
            } else {
                xa[kc] = (float4){0.f, 0.f, 0.f, 0.f};
                xb[kc] = xa[kc];
            }
        }

        f32x4 acc0 = {0.f, 0.f, 0.f, 0.f};
        f32x4 acc1 = {0.f, 0.f, 0.f, 0.f};
        #pragma unroll
        for (int kc = 0; kc < 4; kc++) {
            uint32 u0 = __float_as_uint(xa[kc].x), u1 = __float_as_uint(xa[kc].y);
            uint32 u2 = __float_as_uint(xa[kc].z), u3 = __float_as_uint(xa[kc].w);
            uint32 u4 = __float_as_uint(xb[kc].x), u5 = __float_as_uint(xb[kc].y);
            uint32 u6 = __float_as_uint(xb[kc].z), u7 = __float_as_uint(xb[kc].w);
            FragU ah, al;
            ah.u[0] = pack_hi2(u0, u1);
            ah.u[1] = pack_hi2(u2, u3);
            ah.u[2] = pack_hi2(u4, u5);
            ah.u[3] = pack_hi2(u6, u7);
            float l0 = xa[kc].x - __uint_as_float(u0 & 0xffff0000u);
            float l1 = xa[kc].y - __uint_as_float(u1 & 0xffff0000u);
            float l2 = xa[kc].z - __uint_as_float(u2 & 0xffff0000u);
            float l3 = xa[kc].w - __uint_as_float(u3 & 0xffff0000u);
            float l4 = xb[kc].x - __uint_as_float(u4 & 0xffff0000u);
            float l5 = xb[kc].y - __uint_as_float(u5 & 0xffff0000u);
            float l6 = xb[kc].z - __uint_as_float(u6 & 0xffff0000u);
            float l7 = xb[kc].w - __uint_as_float(u7 & 0xffff0000u);
            al.u[0] = pack_hi2(__float_as_uint(l0), __float_as_uint(l1));
            al.u[1] = pack_hi2(__float_as_uint(l2), __float_as_uint(l3));
            al.u[2] = pack_hi2(__float_as_uint(l4), __float_as_uint(l5));
            al.u[3] = pack_hi2(__float_as_uint(l6), __float_as_uint(l7));
            // 6 MFMAs per kc: hi*hi, hi*lo, lo*hi for both col-tiles
            acc0 = __builtin_amdgcn_mfma_f32_16x16x32_bf16(ah.v, bfr[kc][0].v, acc0, 0, 0, 0);
            acc1 = __builtin_amdgcn_mfma_f32_16x16x32_bf16(ah.v, bfr[kc][1].v, acc1, 0, 0, 0);
            acc0 = __builtin_amdgcn_mfma_f32_16x16x32_bf16(ah.v, bfr[kc + 4][0].v, acc0, 0, 0, 0);
            acc1 = __builtin_amdgcn_mfma_f32_16x16x32_bf16(ah.v, bfr[kc + 4][1].v, acc1, 0, 0, 0);
            acc0 = __builtin_amdgcn_mfma_f32_16x16x32_bf16(al.v, bfr[kc][0].v, acc0, 0, 0, 0);
            acc1 = __builtin_amdgcn_mfma_f32_16x16x32_bf16(al.v, bfr[kc][1].v, acc1, 0, 0, 0);
        }

        // C/D: col = l16 (+16c), row = quad*4 + r; store panel-major, scale by dinv
        #pragma unroll
        for (int r = 0; r < 4; r++) {
            int rr = r0 + quad * 4 + r;
            if (rr < M) {
                float wd = dinv[rowOff + rr];
                size_t i0 = ((size_t)(2 * wv) * Ntot + rowOff + rr) * 16 + l16;
                size_t i1 = ((size_t)(2 * wv + 1) * Ntot + rowOff + rr) * 16 + l16;
                Yhp[i0] = f2bf(acc0[r] * wd);
                Yhp[i1] = f2bf(acc1[r] * wd);
            }
        }
    }
}

// ---------------- launch ----------------

extern "C" void kernel_launch(void* const* d_in, const int* in_sizes, int n_in,
                              void* d_out, int out_size, void* d_ws, size_t ws_size,
                              hipStream_t stream) {
    (void)n_in; (void)out_size; (void)ws_size;
    const float* Gu = (const float*)d_in[0];
    const float* Gi = (const float*)d_in[1];
    const float* W0 = (const float*)d_in[2];
    const float* W1 = (const float*)d_in[3];
    const float* W2 = (const float*)d_in[4];
    const int* ei = (const int*)d_in[5];

    int nu = in_sizes[0] / EMB;          // 60000
    int ni = in_sizes[1] / EMB;          // 40000
    int N = nu + ni;                     // 100000
    int E = in_sizes[5] / 2;             // 2000000
    const int* src = ei;
    const int* dst = ei + E;
    int NB = (N + NPB - 1) / NPB;        // 391

    // workspace layout
    ushort* Yhp     = (ushort*)d_ws;                   // 8 panels x N x 16 bf16 = 25.6 MB
    uint2* ebuf     = (uint2*)(Yhp + (size_t)N * EMB); // E pairs = 16 MB
    int* deg        = (int*)(ebuf + (size_t)E);        // N
    int* rowptr     = deg + N;                         // N+1
    float* dinv     = (float*)(rowptr + N + 1);        // N
    int* csr        = (int*)(dinv + N);                // E
    int* bucket_cnt = csr + E;                         // NB
    int* ebase      = bucket_cnt + NB;                 // NB+1
    int* gcursor    = ebase + NB + 1;                  // NB
    int* bsum       = gcursor + NB;                    // <=128
    ushort* WhiT    = (ushort*)(bsum + 128);           // 3*128*128 bf16
    ushort* WloT    = WhiT + 3 * EMB * EMB;            // 3*128*128 bf16
    float* X        = (float*)d_out;                   // fp32 layer output + final

    hipMemsetAsync(bucket_cnt, 0, sizeof(int) * (size_t)NB, stream);

    wsplit_kernel<<<3, 256, 0, stream>>>(W0, W1, W2, WhiT, WloT);

    int ecb = (E + CHUNK - 1) / CHUNK;                 // 489
    bucket_count_kernel<<<ecb, 256, 0, stream>>>(dst, bucket_cnt, E, NB);
    bucket_scan_kernel<<<1, 512, 0, stream>>>(bucket_cnt, ebase, gcursor, NB, E);
    bucket_scatter_kernel<<<ecb, 256, 0, stream>>>(src, dst, gcursor, ebuf, E, NB);
    bucket_deg_kernel<<<NB, 256, 0, stream>>>(ebuf, ebase, deg, dinv, N);
    int nb = (N + 1023) / 1024;                        // 98
    scan1_kernel<<<nb, 256, 0, stream>>>(deg, rowptr, bsum, N);
    scan2_kernel<<<1, 128, 0, stream>>>(bsum, nb);
    scan3_kernel<<<nb, 256, 0, stream>>>(rowptr, bsum, N, E);
    bucket_fill_kernel<<<NB, 256, 0, stream>>>(ebuf, rowptr, csr, N);

    int aggBlocks = ((N + 31) / 32) * 8;               // node-groups x 8 panels
    const int GB = 1024;                               // gemm grid-stride

    // layer 1: Yhp = dinv * (concat(Gu,Gi) @ W0) (bf16, panel-major), X = relu(agg)
    gemm_mfma_kernel<<<GB, 256, 0, stream>>>(Gu, WhiT, WloT, dinv, Yhp, nu, 0, N);
    gemm_mfma_kernel<<<GB, 256, 0, stream>>>(Gi, WhiT, WloT, dinv, Yhp, ni, nu, N);
    agg_panel_kernel<<<aggBlocks, 256, 0, stream>>>((const uint32*)Yhp, rowptr, csr, dinv, X, N);
    // layer 2
    gemm_mfma_kernel<<<GB, 256, 0, stream>>>(X, WhiT + EMB * EMB, WloT + EMB * EMB, dinv, Yhp, N, 0, N);
    agg_panel_kernel<<<aggBlocks, 256, 0, stream>>>((const uint32*)Yhp, rowptr, csr, dinv, X, N);
    // layer 3
    gemm_mfma_kernel<<<GB, 256, 0, stream>>>(X, WhiT + 2 * EMB * EMB, WloT + 2 * EMB * EMB, dinv, Yhp, N, 0, N);
    agg_panel_kernel<<<aggBlocks, 256, 0, stream>>>((const uint32*)Yhp, rowptr, csr, dinv, X, N);
}